// Round 16
// baseline (249.985 us; speedup 1.0000x reference)
//
#include <hip/hip_runtime.h>
#include <hip/hip_bf16.h>
#include <math.h>

#define NNODES 100000
#define NEDGES 3200000
constexpr int NCHB = (NNODES + 255) / 256; // 391 buckets of 256 nodes
constexpr int NBLK = 256;                  // partition blocks
constexpr int Q4PB = (NEDGES / 4) / NBLK;  // 3125 int4 per block (exact)

typedef __hip_bfloat16 bf16;
typedef __attribute__((ext_vector_type(8))) short bf16x8;
typedef __attribute__((ext_vector_type(4))) float f32x4;

__device__ __forceinline__ bf16 f2b(float v) { return __float2bfloat16(v); }
__device__ __forceinline__ float b2f(bf16 v) { return __bfloat162float(v); }
__device__ __forceinline__ short f2bs(float v) {
    bf16 b = __float2bfloat16(v);
    return *reinterpret_cast<short*>(&b);
}
__device__ __forceinline__ float lo2f(unsigned u) { return __uint_as_float(u << 16); }
__device__ __forceinline__ float hi2f(unsigned u) { return __uint_as_float(u & 0xffff0000u); }

// 8-way compile-time-tree select: returns a[c], c in 0..7
__device__ __forceinline__ float sel8(int c, float a0, float a1, float a2, float a3,
                                      float a4, float a5, float a6, float a7) {
    float b0 = (c & 1) ? a1 : a0, b2 = (c & 1) ? a3 : a2;
    float b4 = (c & 1) ? a5 : a4, b6 = (c & 1) ? a7 : a6;
    float c0 = (c & 2) ? b2 : b0, c4 = (c & 2) ? b6 : b4;
    return (c & 4) ? c4 : c0;
}

// ---------------- CSR build: one-pass radix partition by dst>>8 ----------------

__global__ __launch_bounds__(256) void k_hist2(const int4* __restrict__ dst4,
                                               int* __restrict__ histT,
                                               int* __restrict__ bs) {
    __shared__ int h[NCHB];
    int tid = threadIdx.x, blk = blockIdx.x;
    for (int i = tid; i < NCHB; i += 256) h[i] = 0;
    __syncthreads();
    int base = blk * Q4PB;
    for (int i = tid; i < Q4PB; i += 256) {
        int4 d = dst4[base + i];
        atomicAdd(&h[d.x >> 8], 1);
        atomicAdd(&h[d.y >> 8], 1);
        atomicAdd(&h[d.z >> 8], 1);
        atomicAdd(&h[d.w >> 8], 1);
    }
    __syncthreads();
    for (int i = tid; i < NCHB; i += 256) {
        int v = h[i];
        histT[i * NBLK + blk] = v;
        if (v) atomicAdd(&bs[i], v);   // no result needed -> pipelines
    }
}

__global__ void k_scanbs(const int* __restrict__ bs, int* __restrict__ bse,
                         int* __restrict__ offs) {
    __shared__ int s[512];
    int i = threadIdx.x;
    int v = (i < NCHB) ? bs[i] : 0;
    s[i] = v;
    __syncthreads();
    for (int off = 1; off < 512; off <<= 1) {
        int t = (i >= off) ? s[i - off] : 0;
        __syncthreads();
        s[i] += t;
        __syncthreads();
    }
    if (i < NCHB) bse[i] = s[i] - v;  // exclusive
    if (i == 0) { bse[NCHB] = NEDGES; offs[NNODES] = NEDGES; }
}

__global__ __launch_bounds__(256) void k_scanhist(int* __restrict__ histT,
                                                  const int* __restrict__ bse) {
    int b = blockIdx.x, tid = threadIdx.x;
    int lane = tid & 63, wid = tid >> 6;
    int d = histT[b * NBLK + tid];
    int v = d;  // inclusive wave scan
    { int t = __shfl_up(v, 1);  if (lane >= 1)  v += t; }
    { int t = __shfl_up(v, 2);  if (lane >= 2)  v += t; }
    { int t = __shfl_up(v, 4);  if (lane >= 4)  v += t; }
    { int t = __shfl_up(v, 8);  if (lane >= 8)  v += t; }
    { int t = __shfl_up(v, 16); if (lane >= 16) v += t; }
    { int t = __shfl_up(v, 32); if (lane >= 32) v += t; }
    __shared__ int ws[4];
    if (lane == 63) ws[wid] = v;
    __syncthreads();
    int woff = 0;
#pragma unroll
    for (int i = 0; i < 4; i++) woff += (i < wid) ? ws[i] : 0;
    histT[b * NBLK + tid] = bse[b] + woff + v - d;   // exclusive global base
}

__global__ __launch_bounds__(256) void k_scatter2(const int4* __restrict__ src4,
                                                  const int4* __restrict__ dst4,
                                                  const int* __restrict__ histT,
                                                  int* __restrict__ tmp) {
    __shared__ int cur[NCHB];
    int tid = threadIdx.x, blk = blockIdx.x;
    for (int i = tid; i < NCHB; i += 256) cur[i] = histT[i * NBLK + blk];
    __syncthreads();
    int base = blk * Q4PB;
    for (int i = tid; i < Q4PB; i += 256) {
        int4 s = src4[base + i];
        int4 d = dst4[base + i];
        int b, p;
        b = d.x >> 8; p = atomicAdd(&cur[b], 1); tmp[p] = ((d.x & 255) << 17) | s.x;
        b = d.y >> 8; p = atomicAdd(&cur[b], 1); tmp[p] = ((d.y & 255) << 17) | s.y;
        b = d.z >> 8; p = atomicAdd(&cur[b], 1); tmp[p] = ((d.z & 255) << 17) | s.z;
        b = d.w >> 8; p = atomicAdd(&cur[b], 1); tmp[p] = ((d.w & 255) << 17) | s.w;
    }
}

__global__ __launch_bounds__(256) void k_bucket(const int* __restrict__ tmp,
                                                const int* __restrict__ bse,
                                                int* __restrict__ offs,
                                                float* __restrict__ deginv,
                                                int* __restrict__ csr) {
    int b = blockIdx.x, tid = threadIdx.x;
    int lane = tid & 63, wid = tid >> 6;
    __shared__ int cnt[256], soff[256], ws[4];
    cnt[tid] = 0;
    __syncthreads();
    int s0 = bse[b], s1 = bse[b + 1];
    for (int i = s0 + tid; i < s1; i += 256) atomicAdd(&cnt[tmp[i] >> 17], 1);
    __syncthreads();
    int d = cnt[tid];
    int v = d;  // inclusive wave scan
    { int t = __shfl_up(v, 1);  if (lane >= 1)  v += t; }
    { int t = __shfl_up(v, 2);  if (lane >= 2)  v += t; }
    { int t = __shfl_up(v, 4);  if (lane >= 4)  v += t; }
    { int t = __shfl_up(v, 8);  if (lane >= 8)  v += t; }
    { int t = __shfl_up(v, 16); if (lane >= 16) v += t; }
    { int t = __shfl_up(v, 32); if (lane >= 32) v += t; }
    if (lane == 63) ws[wid] = v;
    __syncthreads();
    int woff = 0;
#pragma unroll
    for (int i = 0; i < 4; i++) woff += (i < wid) ? ws[i] : 0;
    int excl = woff + v - d;
    soff[tid] = excl;
    int node = b * 256 + tid;
    if (node < NNODES) {
        offs[node] = s0 + excl;
        deginv[node] = 1.0f / (float)max(d, 1);
    }
    cnt[tid] = 0;
    __syncthreads();
    for (int i = s0 + tid; i < s1; i += 256) {
        int e = tmp[i];
        int dl = e >> 17, src = e & 0x1FFFF;
        int slot = atomicAdd(&cnt[dl], 1);
        csr[s0 + soff[dl] + slot] = src;
    }
}

// ---- Gather 1: 4 waves/block, 2-stage pipeline. x-gather + w1 + BN/ReLU -> h1 ----

__global__ __launch_bounds__(256) void k_gather1(
    const float* __restrict__ x, const int* __restrict__ csr,
    const int* __restrict__ offs, const float* __restrict__ deginv,
    const float* __restrict__ w1l, const float* __restrict__ w1r,
    const float* __restrict__ b1,
    const float* __restrict__ g1, const float* __restrict__ bb1,
    const float* __restrict__ m1, const float* __restrict__ v1,
    bf16* __restrict__ h1b)
{
    int lane = threadIdx.x & 63, wid = threadIdx.x >> 6;
    float k1 = g1[lane] * rsqrtf(v1[lane] + 1e-5f);
    float c1 = (b1[lane] - m1[lane]) * k1 + bb1[lane];
    float w1lr[8], w1rr[8];
#pragma unroll
    for (int k = 0; k < 8; k++) {
        w1lr[k] = w1l[k * 64 + lane] * k1;
        w1rr[k] = w1r[k * 64 + lane] * k1;
    }

    const float4* xv = (const float4*)x;
    int fh = lane & 1;       // half-row: features 4*fh..4*fh+3
    int g  = lane >> 1;      // 32 edge slots

    int gw = blockIdx.x * 4 + wid;
    int NW = gridDim.x * 4;
    int K = (NNODES + NW - 1) / NW;
    int nbeg = gw * K;
    int nend = min(nbeg + K, NNODES);
    if (nbeg >= nend) return;

    int   stA, dA;  float diA, xsA;  float4 wA0, wA1;
    int   stB, dB;  float diB, xsB;  float4 wB0, wB1;

#define ISS1(NODE, STv, Dv, DIv, XSv, W0, W1) { \
    STv = offs[NODE]; Dv = offs[(NODE) + 1] - STv; \
    DIv = deginv[NODE]; XSv = x[(NODE) * 8 + (lane & 7)]; \
    int c_ = csr[STv + lane]; \
    int dl_ = min(Dv, 64); \
    int s0_ = __shfl(c_, g), s1_ = __shfl(c_, g + 32); \
    W0 = xv[(size_t)((g      < dl_) ? s0_ : 0) * 2 + fh]; \
    W1 = xv[(size_t)((g + 32 < dl_) ? s1_ : 0) * 2 + fh]; \
}

#define CSM1(NODE, STv, Dv, DIv, XSv, W0, W1) { \
    int dl_ = min(Dv, 64); \
    float m0_ = (g < dl_) ? 1.f : 0.f; \
    float m1_ = (g + 32 < dl_) ? 1.f : 0.f; \
    float ax = m0_ * W0.x + m1_ * W1.x; \
    float ay = m0_ * W0.y + m1_ * W1.y; \
    float az = m0_ * W0.z + m1_ * W1.z; \
    float aw = m0_ * W0.w + m1_ * W1.w; \
    for (int i = g + 64; i < Dv; i += 32) {        /* rare tail */ \
        int s = csr[STv + i]; \
        float4 w = xv[(size_t)s * 2 + fh]; \
        ax += w.x; ay += w.y; az += w.z; aw += w.w; \
    } \
    ax += __shfl_xor(ax, 2); ax += __shfl_xor(ax, 4); ax += __shfl_xor(ax, 8); \
    ax += __shfl_xor(ax, 16); ax += __shfl_xor(ax, 32); \
    ay += __shfl_xor(ay, 2); ay += __shfl_xor(ay, 4); ay += __shfl_xor(ay, 8); \
    ay += __shfl_xor(ay, 16); ay += __shfl_xor(ay, 32); \
    az += __shfl_xor(az, 2); az += __shfl_xor(az, 4); az += __shfl_xor(az, 8); \
    az += __shfl_xor(az, 16); az += __shfl_xor(az, 32); \
    aw += __shfl_xor(aw, 2); aw += __shfl_xor(aw, 4); aw += __shfl_xor(aw, 8); \
    aw += __shfl_xor(aw, 16); aw += __shfl_xor(aw, 32); \
    ax *= DIv; ay *= DIv; az *= DIv; aw *= DIv; \
    float h = c1; \
    _Pragma("unroll") \
    for (int k = 0; k < 8; k++) { \
        float comp = ((k & 3) == 0) ? ax : ((k & 3) == 1) ? ay : ((k & 3) == 2) ? az : aw; \
        float a  = __shfl(comp, k >> 2); \
        float xr = __shfl(XSv, k); \
        h = fmaf(a, w1lr[k], fmaf(xr, w1rr[k], h)); \
    } \
    h1b[(size_t)(NODE) * 64 + lane] = f2b(fmaxf(h, 0.f)); \
}

    int n = nbeg;
    ISS1(n, stA, dA, diA, xsA, wA0, wA1)
    for (;;) {
        int nB = (n + 1 < nend) ? n + 1 : n;       // clamp: wasted prefetch at tail
        ISS1(nB, stB, dB, diB, xsB, wB0, wB1)
        CSM1(n, stA, dA, diA, xsA, wA0, wA1)
        if (n + 1 >= nend) break;
        n = nB;
        int nA = (n + 1 < nend) ? n + 1 : n;
        ISS1(nA, stA, dA, diA, xsA, wA0, wA1)
        CSM1(n, stB, dB, diB, xsB, wB0, wB1)
        if (n + 1 >= nend) break;
        n = nA;
    }
#undef ISS1
#undef CSM1
}

// ---- Dense 1 (MFMA): h1 (bf16) -> t2 = h1@(w2l*k2) bf16, r2 = h1@(w2r*k2)+c2 fp32 ----

__global__ __launch_bounds__(64, 2) void k_dense1(
    const bf16* __restrict__ h1b,
    const float* __restrict__ w2l, const float* __restrict__ w2r,
    const float* __restrict__ b2,
    const float* __restrict__ g2, const float* __restrict__ bb2,
    const float* __restrict__ m2, const float* __restrict__ v2,
    bf16* __restrict__ t2, float* __restrict__ r2)
{
    int lane = threadIdx.x;
    int cn = lane & 15, kg = lane >> 4;

    bf16x8 BL[4][2], BR[4][2];
    float c2c[4];
#pragma unroll
    for (int ct = 0; ct < 4; ct++) {
        int col = ct * 16 + cn;
        float k2 = g2[col] * rsqrtf(v2[col] + 1e-5f);
        c2c[ct] = (b2[col] - m2[col]) * k2 + bb2[col];
#pragma unroll
        for (int kh = 0; kh < 2; kh++) {
#pragma unroll
            for (int j = 0; j < 8; j++) {
                int k = kh * 32 + kg * 8 + j;
                BL[ct][kh][j] = f2bs(w2l[k * 64 + col] * k2);
                BR[ct][kh][j] = f2bs(w2r[k * 64 + col] * k2);
            }
        }
    }

    const uint4* hv = (const uint4*)h1b;   // row stride = 8 uint4 (64 bf16)
    int ntiles = NNODES / 16;              // 6250
    for (int t = blockIdx.x; t < ntiles; t += gridDim.x) {
        int row = t * 16 + cn;
        uint4 a0u = hv[(size_t)row * 8 + kg];
        uint4 a1u = hv[(size_t)row * 8 + 4 + kg];
        bf16x8 a0 = *reinterpret_cast<bf16x8*>(&a0u);
        bf16x8 a1 = *reinterpret_cast<bf16x8*>(&a1u);
#pragma unroll
        for (int ct = 0; ct < 4; ct++) {
            f32x4 accT = {0.f, 0.f, 0.f, 0.f};
            f32x4 accR = {c2c[ct], c2c[ct], c2c[ct], c2c[ct]};
            accT = __builtin_amdgcn_mfma_f32_16x16x32_bf16(a0, BL[ct][0], accT, 0, 0, 0);
            accT = __builtin_amdgcn_mfma_f32_16x16x32_bf16(a1, BL[ct][1], accT, 0, 0, 0);
            accR = __builtin_amdgcn_mfma_f32_16x16x32_bf16(a0, BR[ct][0], accR, 0, 0, 0);
            accR = __builtin_amdgcn_mfma_f32_16x16x32_bf16(a1, BR[ct][1], accR, 0, 0, 0);
#pragma unroll
            for (int r = 0; r < 4; r++) {
                int node = t * 16 + kg * 4 + r;
                int col  = ct * 16 + cn;
                t2[(size_t)node * 64 + col] = f2b(accT[r]);
                r2[(size_t)node * 64 + col] = accR[r];
            }
        }
    }
}

// ---- Gather 2: 4 waves/block, 2-stage pipeline. t2-gather + r2 + ReLU -> h2 ----

__global__ __launch_bounds__(256) void k_gather2(
    const bf16* __restrict__ t2, const float* __restrict__ r2,
    const int* __restrict__ csr, const int* __restrict__ offs,
    const float* __restrict__ deginv,
    bf16* __restrict__ h2b)
{
    int lane = threadIdx.x & 63, wid = threadIdx.x >> 6;
    int fq = lane & 7;       // feature octet
    int g  = lane >> 3;      // 8 edge slots
    const uint4* t2v = (const uint4*)t2;

    int gw = blockIdx.x * 4 + wid;
    int NW = gridDim.x * 4;
    int K = (NNODES + NW - 1) / NW;
    int nbeg = gw * K;
    int nend = min(nbeg + K, NNODES);
    if (nbeg >= nend) return;

    int   dA, stA;  float diA, r2A;
    uint4 wA0, wA1, wA2, wA3, wA4, wA5, wA6, wA7;
    int   dB, stB;  float diB, r2B;
    uint4 wB0, wB1, wB2, wB3, wB4, wB5, wB6, wB7;

#define ISS(NODE, Dv, STv, DIv, R2v, W0, W1, W2, W3, W4, W5, W6, W7) { \
    STv = offs[NODE]; Dv = offs[(NODE) + 1] - STv; \
    DIv = deginv[NODE]; R2v = r2[(size_t)(NODE) * 64 + lane]; \
    int c_ = csr[STv + lane]; \
    int dl_ = min(Dv, 64); \
    int s_; \
    s_ = __shfl(c_, g     ); W0 = t2v[(size_t)((g      < dl_) ? s_ : 0) * 8 + fq]; \
    s_ = __shfl(c_, g +  8); W1 = t2v[(size_t)((g +  8 < dl_) ? s_ : 0) * 8 + fq]; \
    s_ = __shfl(c_, g + 16); W2 = t2v[(size_t)((g + 16 < dl_) ? s_ : 0) * 8 + fq]; \
    s_ = __shfl(c_, g + 24); W3 = t2v[(size_t)((g + 24 < dl_) ? s_ : 0) * 8 + fq]; \
    s_ = __shfl(c_, g + 32); W4 = t2v[(size_t)((g + 32 < dl_) ? s_ : 0) * 8 + fq]; \
    s_ = __shfl(c_, g + 40); W5 = t2v[(size_t)((g + 40 < dl_) ? s_ : 0) * 8 + fq]; \
    s_ = __shfl(c_, g + 48); W6 = t2v[(size_t)((g + 48 < dl_) ? s_ : 0) * 8 + fq]; \
    s_ = __shfl(c_, g + 56); W7 = t2v[(size_t)((g + 56 < dl_) ? s_ : 0) * 8 + fq]; \
}

#define L2C(W, M) \
    a0 = fmaf(M, lo2f(W.x), a0); a1 = fmaf(M, hi2f(W.x), a1); \
    a2 = fmaf(M, lo2f(W.y), a2); a3 = fmaf(M, hi2f(W.y), a3); \
    a4 = fmaf(M, lo2f(W.z), a4); a5 = fmaf(M, hi2f(W.z), a5); \
    a6 = fmaf(M, lo2f(W.w), a6); a7 = fmaf(M, hi2f(W.w), a7);
#define R2X(X) X += __shfl_xor(X, 8); X += __shfl_xor(X, 16); X += __shfl_xor(X, 32);

#define CSM(NODE, Dv, STv, DIv, R2v, W0, W1, W2, W3, W4, W5, W6, W7) { \
    int dl_ = min(Dv, 64); \
    float a0 = 0, a1 = 0, a2 = 0, a3 = 0, a4 = 0, a5 = 0, a6 = 0, a7 = 0; \
    L2C(W0, (g      < dl_) ? 1.f : 0.f) \
    L2C(W1, (g +  8 < dl_) ? 1.f : 0.f) \
    L2C(W2, (g + 16 < dl_) ? 1.f : 0.f) \
    L2C(W3, (g + 24 < dl_) ? 1.f : 0.f) \
    L2C(W4, (g + 32 < dl_) ? 1.f : 0.f) \
    L2C(W5, (g + 40 < dl_) ? 1.f : 0.f) \
    L2C(W6, (g + 48 < dl_) ? 1.f : 0.f) \
    L2C(W7, (g + 56 < dl_) ? 1.f : 0.f) \
    for (int i = g + 64; i < Dv; i += 8) {          /* rare tail */ \
        int s = csr[STv + i]; \
        uint4 w = t2v[(size_t)s * 8 + fq]; \
        L2C(w, 1.f) \
    } \
    R2X(a0) R2X(a1) R2X(a2) R2X(a3) R2X(a4) R2X(a5) R2X(a6) R2X(a7) \
    float u = sel8(lane >> 3, a0, a1, a2, a3, a4, a5, a6, a7); \
    int srcl = ((lane & 7) << 3) | (lane >> 3); \
    float vv = __shfl(u, srcl); \
    h2b[(size_t)(NODE) * 64 + lane] = f2b(fmaxf(vv * DIv + R2v, 0.f)); \
}

    int n = nbeg;
    ISS(n, dA, stA, diA, r2A, wA0, wA1, wA2, wA3, wA4, wA5, wA6, wA7)
    for (;;) {
        int nB = (n + 1 < nend) ? n + 1 : n;       // clamp: wasted prefetch at tail
        ISS(nB, dB, stB, diB, r2B, wB0, wB1, wB2, wB3, wB4, wB5, wB6, wB7)
        CSM(n, dA, stA, diA, r2A, wA0, wA1, wA2, wA3, wA4, wA5, wA6, wA7)
        if (n + 1 >= nend) break;
        n = nB;
        int nA = (n + 1 < nend) ? n + 1 : n;
        ISS(nA, dA, stA, diA, r2A, wA0, wA1, wA2, wA3, wA4, wA5, wA6, wA7)
        CSM(n, dB, stB, diB, r2B, wB0, wB1, wB2, wB3, wB4, wB5, wB6, wB7)
        if (n + 1 >= nend) break;
        n = nA;
    }
#undef ISS
#undef L2C
#undef R2X
#undef CSM
}

// ---- Dense 2 (MFMA): h2 (bf16) -> [t3 | r3] = h2 @ [w3l | w3r] (+b3 on r3) ----

__global__ __launch_bounds__(64, 2) void k_dense2(
    const bf16* __restrict__ h2b,
    const float* __restrict__ w3l, const float* __restrict__ w3r,
    const float* __restrict__ b3,
    bf16* __restrict__ t3, float* __restrict__ r3)
{
    int lane = threadIdx.x;
    int cn = lane & 15, kg = lane >> 4;

    bf16x8 Bf[4][2];
    float cini[4];
#pragma unroll
    for (int ct = 0; ct < 4; ct++) {
        int col = ct * 16 + cn;               // 0..63 over [w3l | w3r]
        const float* W = (ct < 2) ? w3l : w3r;
        int cc = col & 31;
        cini[ct] = (ct < 2) ? 0.f : b3[cc];
#pragma unroll
        for (int kh = 0; kh < 2; kh++) {
#pragma unroll
            for (int j = 0; j < 8; j++) {
                int k = kh * 32 + kg * 8 + j;
                Bf[ct][kh][j] = f2bs(W[k * 32 + cc]);
            }
        }
    }

    const uint4* hv = (const uint4*)h2b;
    int ntiles = NNODES / 16;
    for (int t = blockIdx.x; t < ntiles; t += gridDim.x) {
        int row = t * 16 + cn;
        uint4 a0u = hv[(size_t)row * 8 + kg];
        uint4 a1u = hv[(size_t)row * 8 + 4 + kg];
        bf16x8 a0 = *reinterpret_cast<bf16x8*>(&a0u);
        bf16x8 a1 = *reinterpret_cast<bf16x8*>(&a1u);
#pragma unroll
        for (int ct = 0; ct < 4; ct++) {
            f32x4 acc = {cini[ct], cini[ct], cini[ct], cini[ct]};
            acc = __builtin_amdgcn_mfma_f32_16x16x32_bf16(a0, Bf[ct][0], acc, 0, 0, 0);
            acc = __builtin_amdgcn_mfma_f32_16x16x32_bf16(a1, Bf[ct][1], acc, 0, 0, 0);
#pragma unroll
            for (int r = 0; r < 4; r++) {
                int node = t * 16 + kg * 4 + r;
                if (ct < 2) t3[(size_t)node * 32 + ct * 16 + cn] = f2b(acc[r]);
                else        r3[(size_t)node * 32 + (ct - 2) * 16 + cn] = acc[r];
            }
        }
    }
}

// ---- Layer 3: gather t3 (bf16) -> relu(agg+r3) -> fc -> sigmoid ----

__global__ __launch_bounds__(256) void k_layer3(
    const bf16* __restrict__ t3, const float* __restrict__ r3,
    const int* __restrict__ csr, const int* __restrict__ offs,
    const float* __restrict__ deginv,
    const float* __restrict__ fcw, const float* __restrict__ fcb,
    float* __restrict__ out)
{
    int tid = threadIdx.x;
    int lane = tid & 63;
    int node = blockIdx.x * 4 + (tid >> 6);
    if (node >= NNODES) return;

    int o = lane & 31;
    float fcwv = fcw[o];
    float fcbv = fcb[0];

    int start = offs[node];
    int d = offs[node + 1] - start;
    int dl = min(d, 64);
    int c = csr[start + lane];
    float r3v = r3[(size_t)node * 32 + o];

    int fq = lane & 3;
    int g  = lane >> 2;
    const uint4* t3v = (const uint4*)t3;

    int   si[4];
    float mk[4];
#pragma unroll
    for (int t = 0; t < 4; t++) {
        int i = g + 16 * t;
        int s = __shfl(c, i);
        mk[t] = (i < dl) ? 1.f : 0.f;
        si[t] = (i < dl) ? s : 0;
    }
    uint4 w0 = t3v[(size_t)si[0] * 4 + fq];
    uint4 w1 = t3v[(size_t)si[1] * 4 + fq];
    uint4 w2 = t3v[(size_t)si[2] * 4 + fq];
    uint4 w3 = t3v[(size_t)si[3] * 4 + fq];

    float a0 = 0, a1 = 0, a2 = 0, a3 = 0, a4 = 0, a5 = 0, a6 = 0, a7 = 0;
#define CONS(W, M) \
    a0 = fmaf(M, lo2f(W.x), a0); a1 = fmaf(M, hi2f(W.x), a1); \
    a2 = fmaf(M, lo2f(W.y), a2); a3 = fmaf(M, hi2f(W.y), a3); \
    a4 = fmaf(M, lo2f(W.z), a4); a5 = fmaf(M, hi2f(W.z), a5); \
    a6 = fmaf(M, lo2f(W.w), a6); a7 = fmaf(M, hi2f(W.w), a7);
    CONS(w0, mk[0]) CONS(w1, mk[1]) CONS(w2, mk[2]) CONS(w3, mk[3])
    for (int i = g + 64; i < d; i += 16) {
        int s = csr[start + i];
        uint4 w = t3v[(size_t)s * 4 + fq];
        CONS(w, 1.f)
    }
#undef CONS
#define RED3(X) X += __shfl_xor(X, 4); X += __shfl_xor(X, 8); X += __shfl_xor(X, 16); X += __shfl_xor(X, 32);
    RED3(a0) RED3(a1) RED3(a2) RED3(a3) RED3(a4) RED3(a5) RED3(a6) RED3(a7)
#undef RED3
    float u = sel8((lane >> 2) & 7, a0, a1, a2, a3, a4, a5, a6, a7);
    int srcl = ((lane & 7) << 2) | ((lane >> 3) & 3);
    float v = __shfl(u, srcl);

    float h3 = fmaxf(v * deginv[node] + r3v, 0.f);

    float p = h3 * fcwv;
    p += __shfl_xor(p, 1);
    p += __shfl_xor(p, 2);
    p += __shfl_xor(p, 4);
    p += __shfl_xor(p, 8);
    p += __shfl_xor(p, 16);
    if (lane == 0) {
        float z = p + fcbv;
        out[node] = 1.0f / (1.0f + expf(-z));
    }
}

// ---------------- launch ----------------

extern "C" void kernel_launch(void* const* d_in, const int* in_sizes, int n_in,
                              void* d_out, int out_size, void* d_ws, size_t ws_size,
                              hipStream_t stream)
{
    const float* x   = (const float*)d_in[0];
    const int*   ei  = (const int*)d_in[1];
    const int*   src = ei;
    const int*   dst = ei + NEDGES;
    const float* w1l = (const float*)d_in[2];
    const float* w1r = (const float*)d_in[3];
    const float* b1  = (const float*)d_in[4];
    const float* g1  = (const float*)d_in[5];
    const float* bb1 = (const float*)d_in[6];
    const float* m1  = (const float*)d_in[7];
    const float* v1  = (const float*)d_in[8];
    const float* w2l = (const float*)d_in[9];
    const float* w2r = (const float*)d_in[10];
    const float* b2  = (const float*)d_in[11];
    const float* g2  = (const float*)d_in[12];
    const float* bb2 = (const float*)d_in[13];
    const float* m2  = (const float*)d_in[14];
    const float* v2  = (const float*)d_in[15];
    const float* w3l = (const float*)d_in[16];
    const float* w3r = (const float*)d_in[17];
    const float* b3  = (const float*)d_in[18];
    const float* fcw = (const float*)d_in[19];
    const float* fcb = (const float*)d_in[20];

    char* ws = (char*)d_ws;
    size_t off = 0;
    auto alloc = [&](size_t bytes) -> void* {
        void* p = ws + off;
        off += (bytes + 255) & ~(size_t)255;
        return p;
    };
    int*   offs   = (int*)alloc((size_t)(NNODES + 1) * 4);
    int*   bs     = (int*)alloc((size_t)NCHB * 4);
    int*   bse    = (int*)alloc((size_t)(NCHB + 1) * 4);
    int*   histT  = (int*)alloc((size_t)NCHB * NBLK * 4);
    float* deginv = (float*)alloc((size_t)NNODES * 4);
    int*   csr    = (int*)alloc((size_t)(NEDGES + 64) * 4);  // +64 pad
    bf16*  h1b    = (bf16*)alloc((size_t)NNODES * 64 * 2);
    bf16*  t2     = (bf16*)alloc((size_t)NNODES * 64 * 2);
    float* r2     = (float*)alloc((size_t)NNODES * 64 * 4);
    bf16*  h2b    = (bf16*)alloc((size_t)NNODES * 64 * 2);
    bf16*  t3     = (bf16*)alloc((size_t)NNODES * 32 * 2);
    float* r3     = (float*)alloc((size_t)NNODES * 32 * 4);
    int*   tmp    = (int*)r2;   // aliased: consumed by k_bucket before k_dense1 writes r2

    hipMemsetAsync(bs, 0, (size_t)NCHB * 4, stream);

    k_hist2<<<NBLK, 256, 0, stream>>>((const int4*)dst, histT, bs);
    k_scanbs<<<1, 512, 0, stream>>>(bs, bse, offs);
    k_scanhist<<<NCHB, 256, 0, stream>>>(histT, bse);
    k_scatter2<<<NBLK, 256, 0, stream>>>((const int4*)src, (const int4*)dst, histT, tmp);
    k_bucket<<<NCHB, 256, 0, stream>>>(tmp, bse, offs, deginv, csr);

    k_gather1<<<4096, 256, 0, stream>>>(x, csr, offs, deginv,
                                        w1l, w1r, b1, g1, bb1, m1, v1, h1b);
    k_dense1<<<4096, 64, 0, stream>>>(h1b, w2l, w2r, b2, g2, bb2, m2, v2, t2, r2);
    k_gather2<<<4096, 256, 0, stream>>>(t2, r2, csr, offs, deginv, h2b);
    k_dense2<<<4096, 64, 0, stream>>>(h2b, w3l, w3r, b3, t3, r3);
    k_layer3<<<(NNODES + 3) / 4, 256, 0, stream>>>(t3, r3, csr, offs, deginv,
                                                   fcw, fcb, (float*)d_out);
}

// Round 17
// 244.182 us; speedup vs baseline: 1.0238x; 1.0238x over previous
//
#include <hip/hip_runtime.h>
#include <hip/hip_bf16.h>
#include <math.h>

#define NNODES 100000
#define NEDGES 3200000
constexpr int NCHB = (NNODES + 255) / 256; // 391 buckets of 256 nodes
constexpr int NBLK = 256;                  // partition blocks
constexpr int Q4PB = (NEDGES / 4) / NBLK;  // 3125 int4 per block (exact)

typedef __hip_bfloat16 bf16;
typedef __attribute__((ext_vector_type(8))) short bf16x8;
typedef __attribute__((ext_vector_type(4))) float f32x4;

__device__ __forceinline__ bf16 f2b(float v) { return __float2bfloat16(v); }
__device__ __forceinline__ float b2f(bf16 v) { return __bfloat162float(v); }
__device__ __forceinline__ short f2bs(float v) {
    bf16 b = __float2bfloat16(v);
    return *reinterpret_cast<short*>(&b);
}
__device__ __forceinline__ float lo2f(unsigned u) { return __uint_as_float(u << 16); }
__device__ __forceinline__ float hi2f(unsigned u) { return __uint_as_float(u & 0xffff0000u); }

// 8-way compile-time-tree select: returns a[c], c in 0..7
__device__ __forceinline__ float sel8(int c, float a0, float a1, float a2, float a3,
                                      float a4, float a5, float a6, float a7) {
    float b0 = (c & 1) ? a1 : a0, b2 = (c & 1) ? a3 : a2;
    float b4 = (c & 1) ? a5 : a4, b6 = (c & 1) ? a7 : a6;
    float c0 = (c & 2) ? b2 : b0, c4 = (c & 2) ? b6 : b4;
    return (c & 4) ? c4 : c0;
}

// ---------------- CSR build: one-pass radix partition by dst>>8 ----------------

__global__ __launch_bounds__(256) void k_hist2(const int4* __restrict__ dst4,
                                               int* __restrict__ histT,
                                               int* __restrict__ bs) {
    __shared__ int h[NCHB];
    int tid = threadIdx.x, blk = blockIdx.x;
    for (int i = tid; i < NCHB; i += 256) h[i] = 0;
    __syncthreads();
    int base = blk * Q4PB;
    for (int i = tid; i < Q4PB; i += 256) {
        int4 d = dst4[base + i];
        atomicAdd(&h[d.x >> 8], 1);
        atomicAdd(&h[d.y >> 8], 1);
        atomicAdd(&h[d.z >> 8], 1);
        atomicAdd(&h[d.w >> 8], 1);
    }
    __syncthreads();
    for (int i = tid; i < NCHB; i += 256) {
        int v = h[i];
        histT[i * NBLK + blk] = v;
        if (v) atomicAdd(&bs[i], v);   // no result needed -> pipelines
    }
}

__global__ void k_scanbs(const int* __restrict__ bs, int* __restrict__ bse,
                         int* __restrict__ offs) {
    __shared__ int s[512];
    int i = threadIdx.x;
    int v = (i < NCHB) ? bs[i] : 0;
    s[i] = v;
    __syncthreads();
    for (int off = 1; off < 512; off <<= 1) {
        int t = (i >= off) ? s[i - off] : 0;
        __syncthreads();
        s[i] += t;
        __syncthreads();
    }
    if (i < NCHB) bse[i] = s[i] - v;  // exclusive
    if (i == 0) { bse[NCHB] = NEDGES; offs[NNODES] = NEDGES; }
}

__global__ __launch_bounds__(256) void k_scanhist(int* __restrict__ histT,
                                                  const int* __restrict__ bse) {
    int b = blockIdx.x, tid = threadIdx.x;
    int lane = tid & 63, wid = tid >> 6;
    int d = histT[b * NBLK + tid];
    int v = d;  // inclusive wave scan
    { int t = __shfl_up(v, 1);  if (lane >= 1)  v += t; }
    { int t = __shfl_up(v, 2);  if (lane >= 2)  v += t; }
    { int t = __shfl_up(v, 4);  if (lane >= 4)  v += t; }
    { int t = __shfl_up(v, 8);  if (lane >= 8)  v += t; }
    { int t = __shfl_up(v, 16); if (lane >= 16) v += t; }
    { int t = __shfl_up(v, 32); if (lane >= 32) v += t; }
    __shared__ int ws[4];
    if (lane == 63) ws[wid] = v;
    __syncthreads();
    int woff = 0;
#pragma unroll
    for (int i = 0; i < 4; i++) woff += (i < wid) ? ws[i] : 0;
    histT[b * NBLK + tid] = bse[b] + woff + v - d;   // exclusive global base
}

__global__ __launch_bounds__(256) void k_scatter2(const int4* __restrict__ src4,
                                                  const int4* __restrict__ dst4,
                                                  const int* __restrict__ histT,
                                                  int* __restrict__ tmp) {
    __shared__ int cur[NCHB];
    int tid = threadIdx.x, blk = blockIdx.x;
    for (int i = tid; i < NCHB; i += 256) cur[i] = histT[i * NBLK + blk];
    __syncthreads();
    int base = blk * Q4PB;
    for (int i = tid; i < Q4PB; i += 256) {
        int4 s = src4[base + i];
        int4 d = dst4[base + i];
        int b, p;
        b = d.x >> 8; p = atomicAdd(&cur[b], 1); tmp[p] = ((d.x & 255) << 17) | s.x;
        b = d.y >> 8; p = atomicAdd(&cur[b], 1); tmp[p] = ((d.y & 255) << 17) | s.y;
        b = d.z >> 8; p = atomicAdd(&cur[b], 1); tmp[p] = ((d.z & 255) << 17) | s.z;
        b = d.w >> 8; p = atomicAdd(&cur[b], 1); tmp[p] = ((d.w & 255) << 17) | s.w;
    }
}

__global__ __launch_bounds__(256) void k_bucket(const int* __restrict__ tmp,
                                                const int* __restrict__ bse,
                                                int* __restrict__ offs,
                                                float* __restrict__ deginv,
                                                int* __restrict__ csr) {
    int b = blockIdx.x, tid = threadIdx.x;
    int lane = tid & 63, wid = tid >> 6;
    __shared__ int cnt[256], soff[256], ws[4];
    cnt[tid] = 0;
    __syncthreads();
    int s0 = bse[b], s1 = bse[b + 1];
    for (int i = s0 + tid; i < s1; i += 256) atomicAdd(&cnt[tmp[i] >> 17], 1);
    __syncthreads();
    int d = cnt[tid];
    int v = d;  // inclusive wave scan
    { int t = __shfl_up(v, 1);  if (lane >= 1)  v += t; }
    { int t = __shfl_up(v, 2);  if (lane >= 2)  v += t; }
    { int t = __shfl_up(v, 4);  if (lane >= 4)  v += t; }
    { int t = __shfl_up(v, 8);  if (lane >= 8)  v += t; }
    { int t = __shfl_up(v, 16); if (lane >= 16) v += t; }
    { int t = __shfl_up(v, 32); if (lane >= 32) v += t; }
    if (lane == 63) ws[wid] = v;
    __syncthreads();
    int woff = 0;
#pragma unroll
    for (int i = 0; i < 4; i++) woff += (i < wid) ? ws[i] : 0;
    int excl = woff + v - d;
    soff[tid] = excl;
    int node = b * 256 + tid;
    if (node < NNODES) {
        offs[node] = s0 + excl;
        deginv[node] = 1.0f / (float)max(d, 1);
    }
    cnt[tid] = 0;
    __syncthreads();
    for (int i = s0 + tid; i < s1; i += 256) {
        int e = tmp[i];
        int dl = e >> 17, src = e & 0x1FFFF;
        int slot = atomicAdd(&cnt[dl], 1);
        csr[s0 + soff[dl] + slot] = src;
    }
}

// ---- Gather 1: 4 waves/block, each wave one node. x-gather + w1 + BN/ReLU -> h1 ----

__global__ __launch_bounds__(256) void k_gather1(
    const float* __restrict__ x, const int* __restrict__ csr,
    const int* __restrict__ offs, const float* __restrict__ deginv,
    const float* __restrict__ w1l, const float* __restrict__ w1r,
    const float* __restrict__ b1,
    const float* __restrict__ g1, const float* __restrict__ bb1,
    const float* __restrict__ m1, const float* __restrict__ v1,
    bf16* __restrict__ h1b)
{
    int lane = threadIdx.x & 63, wid = threadIdx.x >> 6;
    float k1 = g1[lane] * rsqrtf(v1[lane] + 1e-5f);
    float c1 = (b1[lane] - m1[lane]) * k1 + bb1[lane];
    float w1lr[8], w1rr[8];
#pragma unroll
    for (int k = 0; k < 8; k++) {
        w1lr[k] = w1l[k * 64 + lane] * k1;
        w1rr[k] = w1r[k * 64 + lane] * k1;
    }

    const float4* xv = (const float4*)x;
    int fh = lane & 1;       // half-row: features 4*fh..4*fh+3
    int g  = lane >> 1;      // 32 edge slots

    for (int node = blockIdx.x * 4 + wid; node < NNODES; node += gridDim.x * 4) {
        int start = offs[node];
        int d = offs[node + 1] - start;
        int dl = min(d, 64);
        int c = csr[start + lane];                 // csr padded +64
        float xs = x[node * 8 + (lane & 7)];

        int s0 = __shfl(c, g), s1 = __shfl(c, g + 32);
        float4 w0 = xv[(size_t)((g      < dl) ? s0 : 0) * 2 + fh];
        float4 w1v = xv[(size_t)((g + 32 < dl) ? s1 : 0) * 2 + fh];
        float m0 = (g < dl) ? 1.f : 0.f;
        float m1f = (g + 32 < dl) ? 1.f : 0.f;
        float ax = m0 * w0.x + m1f * w1v.x;
        float ay = m0 * w0.y + m1f * w1v.y;
        float az = m0 * w0.z + m1f * w1v.z;
        float aw = m0 * w0.w + m1f * w1v.w;
        for (int i = g + 64; i < d; i += 32) {     // rare tail
            int s = csr[start + i];
            float4 w = xv[(size_t)s * 2 + fh];
            ax += w.x; ay += w.y; az += w.z; aw += w.w;
        }
#define RED1(X) X += __shfl_xor(X, 2); X += __shfl_xor(X, 4); X += __shfl_xor(X, 8); \
                X += __shfl_xor(X, 16); X += __shfl_xor(X, 32);
        RED1(ax) RED1(ay) RED1(az) RED1(aw)
#undef RED1
        float di = deginv[node];
        ax *= di; ay *= di; az *= di; aw *= di;

        float h = c1;
#pragma unroll
        for (int k = 0; k < 8; k++) {
            float comp = ((k & 3) == 0) ? ax : ((k & 3) == 1) ? ay : ((k & 3) == 2) ? az : aw;
            float a  = __shfl(comp, k >> 2);
            float xr = __shfl(xs, k);
            h = fmaf(a, w1lr[k], fmaf(xr, w1rr[k], h));
        }
        h1b[(size_t)node * 64 + lane] = f2b(fmaxf(h, 0.f));
    }
}

// ---- Dense 1 (MFMA): h1 (bf16) -> t2 = h1@(w2l*k2) bf16, r2 = h1@(w2r*k2)+c2 fp32 ----

__global__ __launch_bounds__(64, 2) void k_dense1(
    const bf16* __restrict__ h1b,
    const float* __restrict__ w2l, const float* __restrict__ w2r,
    const float* __restrict__ b2,
    const float* __restrict__ g2, const float* __restrict__ bb2,
    const float* __restrict__ m2, const float* __restrict__ v2,
    bf16* __restrict__ t2, float* __restrict__ r2)
{
    int lane = threadIdx.x;
    int cn = lane & 15, kg = lane >> 4;

    bf16x8 BL[4][2], BR[4][2];
    float c2c[4];
#pragma unroll
    for (int ct = 0; ct < 4; ct++) {
        int col = ct * 16 + cn;
        float k2 = g2[col] * rsqrtf(v2[col] + 1e-5f);
        c2c[ct] = (b2[col] - m2[col]) * k2 + bb2[col];
#pragma unroll
        for (int kh = 0; kh < 2; kh++) {
#pragma unroll
            for (int j = 0; j < 8; j++) {
                int k = kh * 32 + kg * 8 + j;
                BL[ct][kh][j] = f2bs(w2l[k * 64 + col] * k2);
                BR[ct][kh][j] = f2bs(w2r[k * 64 + col] * k2);
            }
        }
    }

    const uint4* hv = (const uint4*)h1b;   // row stride = 8 uint4 (64 bf16)
    int ntiles = NNODES / 16;              // 6250
    for (int t = blockIdx.x; t < ntiles; t += gridDim.x) {
        int row = t * 16 + cn;
        uint4 a0u = hv[(size_t)row * 8 + kg];
        uint4 a1u = hv[(size_t)row * 8 + 4 + kg];
        bf16x8 a0 = *reinterpret_cast<bf16x8*>(&a0u);
        bf16x8 a1 = *reinterpret_cast<bf16x8*>(&a1u);
#pragma unroll
        for (int ct = 0; ct < 4; ct++) {
            f32x4 accT = {0.f, 0.f, 0.f, 0.f};
            f32x4 accR = {c2c[ct], c2c[ct], c2c[ct], c2c[ct]};
            accT = __builtin_amdgcn_mfma_f32_16x16x32_bf16(a0, BL[ct][0], accT, 0, 0, 0);
            accT = __builtin_amdgcn_mfma_f32_16x16x32_bf16(a1, BL[ct][1], accT, 0, 0, 0);
            accR = __builtin_amdgcn_mfma_f32_16x16x32_bf16(a0, BR[ct][0], accR, 0, 0, 0);
            accR = __builtin_amdgcn_mfma_f32_16x16x32_bf16(a1, BR[ct][1], accR, 0, 0, 0);
#pragma unroll
            for (int r = 0; r < 4; r++) {
                int node = t * 16 + kg * 4 + r;
                int col  = ct * 16 + cn;
                t2[(size_t)node * 64 + col] = f2b(accT[r]);
                r2[(size_t)node * 64 + col] = accR[r];
            }
        }
    }
}

// ---- Gather 2: 4 waves/block, each wave one node. t2-gather + r2 + ReLU -> h2 ----

__global__ __launch_bounds__(256) void k_gather2(
    const bf16* __restrict__ t2, const float* __restrict__ r2,
    const int* __restrict__ csr, const int* __restrict__ offs,
    const float* __restrict__ deginv,
    bf16* __restrict__ h2b)
{
    int lane = threadIdx.x & 63, wid = threadIdx.x >> 6;
    int fq = lane & 7;       // feature octet
    int g  = lane >> 3;      // 8 edge slots
    const uint4* t2v = (const uint4*)t2;

    for (int node = blockIdx.x * 4 + wid; node < NNODES; node += gridDim.x * 4) {
        int start = offs[node];
        int d = offs[node + 1] - start;
        int dl = min(d, 64);
        int c = csr[start + lane];
        float r2v = r2[(size_t)node * 64 + lane];
        float di = deginv[node];

        int s;
        s = __shfl(c, g     ); uint4 w0 = t2v[(size_t)((g      < dl) ? s : 0) * 8 + fq];
        s = __shfl(c, g +  8); uint4 w1 = t2v[(size_t)((g +  8 < dl) ? s : 0) * 8 + fq];
        s = __shfl(c, g + 16); uint4 w2 = t2v[(size_t)((g + 16 < dl) ? s : 0) * 8 + fq];
        s = __shfl(c, g + 24); uint4 w3 = t2v[(size_t)((g + 24 < dl) ? s : 0) * 8 + fq];
        s = __shfl(c, g + 32); uint4 w4 = t2v[(size_t)((g + 32 < dl) ? s : 0) * 8 + fq];
        s = __shfl(c, g + 40); uint4 w5 = t2v[(size_t)((g + 40 < dl) ? s : 0) * 8 + fq];
        s = __shfl(c, g + 48); uint4 w6 = t2v[(size_t)((g + 48 < dl) ? s : 0) * 8 + fq];
        s = __shfl(c, g + 56); uint4 w7 = t2v[(size_t)((g + 56 < dl) ? s : 0) * 8 + fq];

        float a0 = 0, a1 = 0, a2 = 0, a3 = 0, a4 = 0, a5 = 0, a6 = 0, a7 = 0;
#define CONS(W, M) \
        a0 = fmaf(M, lo2f(W.x), a0); a1 = fmaf(M, hi2f(W.x), a1); \
        a2 = fmaf(M, lo2f(W.y), a2); a3 = fmaf(M, hi2f(W.y), a3); \
        a4 = fmaf(M, lo2f(W.z), a4); a5 = fmaf(M, hi2f(W.z), a5); \
        a6 = fmaf(M, lo2f(W.w), a6); a7 = fmaf(M, hi2f(W.w), a7);
        CONS(w0, (g      < dl) ? 1.f : 0.f)
        CONS(w1, (g +  8 < dl) ? 1.f : 0.f)
        CONS(w2, (g + 16 < dl) ? 1.f : 0.f)
        CONS(w3, (g + 24 < dl) ? 1.f : 0.f)
        CONS(w4, (g + 32 < dl) ? 1.f : 0.f)
        CONS(w5, (g + 40 < dl) ? 1.f : 0.f)
        CONS(w6, (g + 48 < dl) ? 1.f : 0.f)
        CONS(w7, (g + 56 < dl) ? 1.f : 0.f)
        for (int i = g + 64; i < d; i += 8) {       // rare tail
            int ss = csr[start + i];
            uint4 w = t2v[(size_t)ss * 8 + fq];
            CONS(w, 1.f)
        }
#undef CONS
#define RED2(X) X += __shfl_xor(X, 8); X += __shfl_xor(X, 16); X += __shfl_xor(X, 32);
        RED2(a0) RED2(a1) RED2(a2) RED2(a3) RED2(a4) RED2(a5) RED2(a6) RED2(a7)
#undef RED2
        float u = sel8(lane >> 3, a0, a1, a2, a3, a4, a5, a6, a7);
        int srcl = ((lane & 7) << 3) | (lane >> 3);
        float v = __shfl(u, srcl);

        h2b[(size_t)node * 64 + lane] = f2b(fmaxf(v * di + r2v, 0.f));
    }
}

// ---- Dense 2 (MFMA): h2 (bf16) -> [t3 | r3] = h2 @ [w3l | w3r] (+b3 on r3) ----

__global__ __launch_bounds__(64, 2) void k_dense2(
    const bf16* __restrict__ h2b,
    const float* __restrict__ w3l, const float* __restrict__ w3r,
    const float* __restrict__ b3,
    bf16* __restrict__ t3, float* __restrict__ r3)
{
    int lane = threadIdx.x;
    int cn = lane & 15, kg = lane >> 4;

    bf16x8 Bf[4][2];
    float cini[4];
#pragma unroll
    for (int ct = 0; ct < 4; ct++) {
        int col = ct * 16 + cn;               // 0..63 over [w3l | w3r]
        const float* W = (ct < 2) ? w3l : w3r;
        int cc = col & 31;
        cini[ct] = (ct < 2) ? 0.f : b3[cc];
#pragma unroll
        for (int kh = 0; kh < 2; kh++) {
#pragma unroll
            for (int j = 0; j < 8; j++) {
                int k = kh * 32 + kg * 8 + j;
                Bf[ct][kh][j] = f2bs(W[k * 32 + cc]);
            }
        }
    }

    const uint4* hv = (const uint4*)h2b;
    int ntiles = NNODES / 16;
    for (int t = blockIdx.x; t < ntiles; t += gridDim.x) {
        int row = t * 16 + cn;
        uint4 a0u = hv[(size_t)row * 8 + kg];
        uint4 a1u = hv[(size_t)row * 8 + 4 + kg];
        bf16x8 a0 = *reinterpret_cast<bf16x8*>(&a0u);
        bf16x8 a1 = *reinterpret_cast<bf16x8*>(&a1u);
#pragma unroll
        for (int ct = 0; ct < 4; ct++) {
            f32x4 acc = {cini[ct], cini[ct], cini[ct], cini[ct]};
            acc = __builtin_amdgcn_mfma_f32_16x16x32_bf16(a0, Bf[ct][0], acc, 0, 0, 0);
            acc = __builtin_amdgcn_mfma_f32_16x16x32_bf16(a1, Bf[ct][1], acc, 0, 0, 0);
#pragma unroll
            for (int r = 0; r < 4; r++) {
                int node = t * 16 + kg * 4 + r;
                if (ct < 2) t3[(size_t)node * 32 + ct * 16 + cn] = f2b(acc[r]);
                else        r3[(size_t)node * 32 + (ct - 2) * 16 + cn] = acc[r];
            }
        }
    }
}

// ---- Layer 3: gather t3 (bf16) -> relu(agg+r3) -> fc -> sigmoid ----

__global__ __launch_bounds__(256) void k_layer3(
    const bf16* __restrict__ t3, const float* __restrict__ r3,
    const int* __restrict__ csr, const int* __restrict__ offs,
    const float* __restrict__ deginv,
    const float* __restrict__ fcw, const float* __restrict__ fcb,
    float* __restrict__ out)
{
    int tid = threadIdx.x;
    int lane = tid & 63;
    int node = blockIdx.x * 4 + (tid >> 6);
    if (node >= NNODES) return;

    int o = lane & 31;
    float fcwv = fcw[o];
    float fcbv = fcb[0];

    int start = offs[node];
    int d = offs[node + 1] - start;
    int dl = min(d, 64);
    int c = csr[start + lane];
    float r3v = r3[(size_t)node * 32 + o];

    int fq = lane & 3;
    int g  = lane >> 2;
    const uint4* t3v = (const uint4*)t3;

    int   si[4];
    float mk[4];
#pragma unroll
    for (int t = 0; t < 4; t++) {
        int i = g + 16 * t;
        int s = __shfl(c, i);
        mk[t] = (i < dl) ? 1.f : 0.f;
        si[t] = (i < dl) ? s : 0;
    }
    uint4 w0 = t3v[(size_t)si[0] * 4 + fq];
    uint4 w1 = t3v[(size_t)si[1] * 4 + fq];
    uint4 w2 = t3v[(size_t)si[2] * 4 + fq];
    uint4 w3 = t3v[(size_t)si[3] * 4 + fq];

    float a0 = 0, a1 = 0, a2 = 0, a3 = 0, a4 = 0, a5 = 0, a6 = 0, a7 = 0;
#define CONS(W, M) \
    a0 = fmaf(M, lo2f(W.x), a0); a1 = fmaf(M, hi2f(W.x), a1); \
    a2 = fmaf(M, lo2f(W.y), a2); a3 = fmaf(M, hi2f(W.y), a3); \
    a4 = fmaf(M, lo2f(W.z), a4); a5 = fmaf(M, hi2f(W.z), a5); \
    a6 = fmaf(M, lo2f(W.w), a6); a7 = fmaf(M, hi2f(W.w), a7);
    CONS(w0, mk[0]) CONS(w1, mk[1]) CONS(w2, mk[2]) CONS(w3, mk[3])
    for (int i = g + 64; i < d; i += 16) {
        int s = csr[start + i];
        uint4 w = t3v[(size_t)s * 4 + fq];
        CONS(w, 1.f)
    }
#undef CONS
#define RED3(X) X += __shfl_xor(X, 4); X += __shfl_xor(X, 8); X += __shfl_xor(X, 16); X += __shfl_xor(X, 32);
    RED3(a0) RED3(a1) RED3(a2) RED3(a3) RED3(a4) RED3(a5) RED3(a6) RED3(a7)
#undef RED3
    float u = sel8((lane >> 2) & 7, a0, a1, a2, a3, a4, a5, a6, a7);
    int srcl = ((lane & 7) << 2) | ((lane >> 3) & 3);
    float v = __shfl(u, srcl);

    float h3 = fmaxf(v * deginv[node] + r3v, 0.f);

    float p = h3 * fcwv;
    p += __shfl_xor(p, 1);
    p += __shfl_xor(p, 2);
    p += __shfl_xor(p, 4);
    p += __shfl_xor(p, 8);
    p += __shfl_xor(p, 16);
    if (lane == 0) {
        float z = p + fcbv;
        out[node] = 1.0f / (1.0f + expf(-z));
    }
}

// ---------------- launch ----------------

extern "C" void kernel_launch(void* const* d_in, const int* in_sizes, int n_in,
                              void* d_out, int out_size, void* d_ws, size_t ws_size,
                              hipStream_t stream)
{
    const float* x   = (const float*)d_in[0];
    const int*   ei  = (const int*)d_in[1];
    const int*   src = ei;
    const int*   dst = ei + NEDGES;
    const float* w1l = (const float*)d_in[2];
    const float* w1r = (const float*)d_in[3];
    const float* b1  = (const float*)d_in[4];
    const float* g1  = (const float*)d_in[5];
    const float* bb1 = (const float*)d_in[6];
    const float* m1  = (const float*)d_in[7];
    const float* v1  = (const float*)d_in[8];
    const float* w2l = (const float*)d_in[9];
    const float* w2r = (const float*)d_in[10];
    const float* b2  = (const float*)d_in[11];
    const float* g2  = (const float*)d_in[12];
    const float* bb2 = (const float*)d_in[13];
    const float* m2  = (const float*)d_in[14];
    const float* v2  = (const float*)d_in[15];
    const float* w3l = (const float*)d_in[16];
    const float* w3r = (const float*)d_in[17];
    const float* b3  = (const float*)d_in[18];
    const float* fcw = (const float*)d_in[19];
    const float* fcb = (const float*)d_in[20];

    char* ws = (char*)d_ws;
    size_t off = 0;
    auto alloc = [&](size_t bytes) -> void* {
        void* p = ws + off;
        off += (bytes + 255) & ~(size_t)255;
        return p;
    };
    int*   offs   = (int*)alloc((size_t)(NNODES + 1) * 4);
    int*   bs     = (int*)alloc((size_t)NCHB * 4);
    int*   bse    = (int*)alloc((size_t)(NCHB + 1) * 4);
    int*   histT  = (int*)alloc((size_t)NCHB * NBLK * 4);
    float* deginv = (float*)alloc((size_t)NNODES * 4);
    int*   csr    = (int*)alloc((size_t)(NEDGES + 64) * 4);  // +64 pad
    bf16*  h1b    = (bf16*)alloc((size_t)NNODES * 64 * 2);
    bf16*  t2     = (bf16*)alloc((size_t)NNODES * 64 * 2);
    float* r2     = (float*)alloc((size_t)NNODES * 64 * 4);
    bf16*  h2b    = (bf16*)alloc((size_t)NNODES * 64 * 2);
    bf16*  t3     = (bf16*)alloc((size_t)NNODES * 32 * 2);
    float* r3     = (float*)alloc((size_t)NNODES * 32 * 4);
    int*   tmp    = (int*)r2;   // aliased: consumed by k_bucket before k_dense1 writes r2

    hipMemsetAsync(bs, 0, (size_t)NCHB * 4, stream);

    k_hist2<<<NBLK, 256, 0, stream>>>((const int4*)dst, histT, bs);
    k_scanbs<<<1, 512, 0, stream>>>(bs, bse, offs);
    k_scanhist<<<NCHB, 256, 0, stream>>>(histT, bse);
    k_scatter2<<<NBLK, 256, 0, stream>>>((const int4*)src, (const int4*)dst, histT, tmp);
    k_bucket<<<NCHB, 256, 0, stream>>>(tmp, bse, offs, deginv, csr);

    k_gather1<<<4096, 256, 0, stream>>>(x, csr, offs, deginv,
                                        w1l, w1r, b1, g1, bb1, m1, v1, h1b);
    k_dense1<<<4096, 64, 0, stream>>>(h1b, w2l, w2r, b2, g2, bb2, m2, v2, t2, r2);
    k_gather2<<<4096, 256, 0, stream>>>(t2, r2, csr, offs, deginv, h2b);
    k_dense2<<<4096, 64, 0, stream>>>(h2b, w3l, w3r, b3, t3, r3);
    k_layer3<<<(NNODES + 3) / 4, 256, 0, stream>>>(t3, r3, csr, offs, deginv,
                                                   fcw, fcb, (float*)d_out);
}